// Round 1
// baseline (253.583 us; speedup 1.0000x reference)
//
#include <hip/hip_runtime.h>

// Problem constants (from reference setup_inputs): B=4, C=64, H=256, W=512
constexpr int B = 4;
constexpr int C = 64;
constexpr int H = 256;
constexpr int W = 512;

// One thread computes 4 consecutive-w outputs (float4 store).
// Per-pixel params (ry, wa, wb, idx) depend only on (b,h,w); disp is [B,1,H,W]
// and fits in L2 (2 MiB), so re-reading it per-channel is cheap.
__global__ __launch_bounds__(256) void spatial_warp_kernel(
    const float* __restrict__ input,   // [B,C,H,W]
    const float* __restrict__ disp,    // [B,1,H,W]
    float* __restrict__ out)           // [B,C,H,W]
{
    const long long tid  = (long long)blockIdx.x * blockDim.x + threadIdx.x;
    const long long idx4 = tid * 4;                  // flat elem index, w-fastest
    if (idx4 >= (long long)B * C * H * W) return;

    const int w0 = (int)(idx4 % W);
    long long rest = idx4 / W;
    const int h = (int)(rest % H);
    rest /= H;
    const int c = (int)(rest % C);
    const int b = (int)(rest / C);

    // disp index: [b,0,h,w]
    const long long pix = ((long long)b * H + h) * W + w0;
    const float4 d4 = *reinterpret_cast<const float4*>(disp + pix);

    const float* __restrict__ row =
        input + (((long long)b * C + c) * H + h) * (long long)W;

    const float dv[4] = {d4.x, d4.y, d4.z, d4.w};
    float ov[4];

#pragma unroll
    for (int i = 0; i < 4; ++i) {
        const float ry  = (float)(w0 + i) + dv[i];
        const float ra  = floorf(ry);
        const float rb  = ra + 1.0f;
        const float wa_ = rb - ry;   // match reference arithmetic exactly
        const float wb_ = ry - ra;
        // clip the FLOAT coordinate (as reference does), then cast
        const float ra_c = fminf(fmaxf(ra, 0.0f), (float)(W - 1));
        const float rb_c = fminf(fmaxf(rb, 0.0f), (float)(W - 1));
        const int ia = (int)ra_c;
        const int ib = (int)rb_c;
        const float fa = row[ia];
        const float fb = row[ib];
        const float val = wa_ * fa + wb_ * fb;
        const bool valid = (ry >= 0.0f) && (ry <= (float)(W - 1));
        ov[i] = valid ? val : 0.0f;
    }

    float4 o;
    o.x = ov[0]; o.y = ov[1]; o.z = ov[2]; o.w = ov[3];
    *reinterpret_cast<float4*>(out + idx4) = o;
}

extern "C" void kernel_launch(void* const* d_in, const int* in_sizes, int n_in,
                              void* d_out, int out_size, void* d_ws, size_t ws_size,
                              hipStream_t stream) {
    const float* input = (const float*)d_in[0];   // right_input [B,C,H,W] fp32
    const float* disp  = (const float*)d_in[1];   // disparity_samples [B,1,H,W] fp32
    float* out = (float*)d_out;

    const long long total   = (long long)B * C * H * W;   // 33,554,432
    const long long threads = total / 4;                  // 8,388,608
    const int block = 256;
    const int grid  = (int)((threads + block - 1) / block);

    spatial_warp_kernel<<<grid, block, 0, stream>>>(input, disp, out);
}

// Round 2
// 234.456 us; speedup vs baseline: 1.0816x; 1.0816x over previous
//
#include <hip/hip_runtime.h>

// Problem constants: B=4, C=64, H=256, W=512 (fp32)
constexpr int B = 4;
constexpr int C = 64;
constexpr int H = 256;
constexpr int W = 512;
constexpr int CH_PER_BLOCK = 16;   // channels handled by one block
constexpr int ROWS_PER_ITER = 2;   // channels staged in LDS per iteration

// Block (256 threads) = one (b,h) pixel-row, 16 channels.
// Phase 1: stage disp row in LDS, precompute per-thread warp params
//          (each thread owns w = lane + 128*i, i=0..3; fixed across channels).
// Phase 2: per channel-pair: coalesced float4 row load -> LDS,
//          stride-1 conflict-free LDS gathers, coalesced dword stores.
__global__ __launch_bounds__(256) void spatial_warp_kernel(
    const float* __restrict__ input,   // [B,C,H,W]
    const float* __restrict__ disp,    // [B,1,H,W]
    float* __restrict__ out)           // [B,C,H,W]
{
    __shared__ float s_row[ROWS_PER_ITER * W];  // 4 KiB
    __shared__ float s_disp[W];                 // 2 KiB

    const int t = threadIdx.x;
    const int cg = blockIdx.x % (C / CH_PER_BLOCK);
    int rest = blockIdx.x / (C / CH_PER_BLOCK);
    const int h = rest % H;
    const int b = rest / H;
    const int c_base = cg * CH_PER_BLOCK;

    // ---- Phase 1: stage disp row, precompute warp params ----
    const long long pix_base = ((long long)b * H + h) * W;
    if (t < W / 4) {
        reinterpret_cast<float4*>(s_disp)[t] =
            reinterpret_cast<const float4*>(disp + pix_base)[t];
    }
    __syncthreads();

    const int r     = t >> 7;      // which of the 2 staged rows this thread reads
    const int lane7 = t & 127;     // position within the half-block

    float wa4[4], wb4[4], msk[4];
    int   ia4[4], ib4[4];
#pragma unroll
    for (int i = 0; i < 4; ++i) {
        const int w  = lane7 + 128 * i;
        const float d  = s_disp[w];
        const float ry = (float)w + d;
        const float ra = floorf(ry);
        const float rb = ra + 1.0f;
        wa4[i] = rb - ry;
        wb4[i] = ry - ra;
        // clip float coordinate (as reference), then cast -> safe for any disp
        ia4[i] = (int)fminf(fmaxf(ra, 0.0f), (float)(W - 1));
        ib4[i] = (int)fminf(fmaxf(rb, 0.0f), (float)(W - 1));
        msk[i] = (ry >= 0.0f && ry <= (float)(W - 1)) ? 1.0f : 0.0f;
    }

    // ---- Phase 2: channel loop, 2 rows per iteration ----
    const int lds_base = r * W;
#pragma unroll 2
    for (int cc = 0; cc < CH_PER_BLOCK / ROWS_PER_ITER; ++cc) {
        const int c_mine = c_base + cc * ROWS_PER_ITER + r;
        const float* rowg = input + (((long long)b * C + c_mine) * H + h) * (long long)W;
        // coalesced float4 load of my half's row into LDS
        const float4 v = reinterpret_cast<const float4*>(rowg)[lane7];
        __syncthreads();  // protect previous iteration's LDS reads
        reinterpret_cast<float4*>(s_row + lds_base)[lane7] = v;
        __syncthreads();

        float* outg = out + (((long long)b * C + c_mine) * H + h) * (long long)W;
#pragma unroll
        for (int i = 0; i < 4; ++i) {
            const int w = lane7 + 128 * i;
            const float fa = s_row[lds_base + ia4[i]];
            const float fb = s_row[lds_base + ib4[i]];
            outg[w] = msk[i] * (wa4[i] * fa + wb4[i] * fb);
        }
    }
}

extern "C" void kernel_launch(void* const* d_in, const int* in_sizes, int n_in,
                              void* d_out, int out_size, void* d_ws, size_t ws_size,
                              hipStream_t stream) {
    const float* input = (const float*)d_in[0];   // right_input [B,C,H,W]
    const float* disp  = (const float*)d_in[1];   // disparity_samples [B,1,H,W]
    float* outp = (float*)d_out;

    const int grid = B * H * (C / CH_PER_BLOCK);  // 4*256*4 = 4096 blocks
    spatial_warp_kernel<<<grid, 256, 0, stream>>>(input, disp, outp);
}